// Round 1
// baseline (219.904 us; speedup 1.0000x reference)
//
#include <hip/hip_runtime.h>

#define EMBED 1024
#define NHEAD 16
#define HDIM  64
#define BATCH 2
#define SEQ   2048
#define MTOK  (BATCH * SEQ)   // 4096 tokens
#define QSCALE 0.1803368801f  // (1/sqrt(64)) * log2(e): softmax done in base 2

typedef __bf16 bf16x8 __attribute__((ext_vector_type(8)));
typedef float  f32x4  __attribute__((ext_vector_type(4)));

// round-half-up f32->bf16 (bias <= 2^-25, well under harness threshold)
__device__ __forceinline__ unsigned short f2bf(float f) {
  return (unsigned short)((__float_as_uint(f) + 0x8000u) >> 16);
}
// pack two f32 -> bf16x2 in one v_perm
__device__ __forceinline__ unsigned int pkbf(float a, float b) {
  unsigned int ua = __float_as_uint(a) + 0x8000u;
  unsigned int ub = __float_as_uint(b) + 0x8000u;
  return __builtin_amdgcn_perm(ub, ua, 0x07060302u);
}

// async global->LDS, 16B/lane; LDS dest = wave-uniform base + lane*16
__device__ __forceinline__ void gload_lds16(const unsigned short* g, unsigned short* l) {
  __builtin_amdgcn_global_load_lds((__attribute__((address_space(1))) void*)g,
                                   (__attribute__((address_space(3))) void*)l, 16, 0, 0);
}

// ---------------- prep: cast X -> bf16 (blocks 0..4095) + 4 weight transpose-casts ----------
__global__ __launch_bounds__(256)
void prep_k(const float* __restrict__ X, unsigned short* __restrict__ Xbf,
            const float* __restrict__ w0, const float* __restrict__ w1,
            const float* __restrict__ w2, const float* __restrict__ w3,
            unsigned short* __restrict__ t0, unsigned short* __restrict__ t1,
            unsigned short* __restrict__ t2, unsigned short* __restrict__ t3) {
  const int id = blockIdx.x;
  if (id < 4096) {                          // cast: 1M uint2 = 4M floats
    int i = id * 256 + threadIdx.x;
    float4 f = reinterpret_cast<const float4*>(X)[i];
    reinterpret_cast<uint2*>(Xbf)[i] = make_uint2(pkbf(f.x, f.y), pkbf(f.z, f.w));
    return;
  }
  const int t = id - 4096;                  // 0..1023: 4 weights x 256 tiles
  const float* s; unsigned short* d;
  switch (t >> 8) {
    case 0: s = w0; d = t0; break;
    case 1: s = w1; d = t1; break;
    case 2: s = w2; d = t2; break;
    default: s = w3; d = t3; break;
  }
  const int tt = t & 255;
  const int k0 = (tt >> 4) * 64, n0 = (tt & 15) * 64;
  __shared__ unsigned short T[64][65];
  for (int i = threadIdx.x; i < 4096; i += 256) {
    int r = i >> 6, c = i & 63;             // read coalesced over n
    T[c][r] = f2bf(s[(size_t)(k0 + r) * EMBED + n0 + c]);
  }
  __syncthreads();
  for (int i = threadIdx.x; i < 4096; i += 256) {
    int r = i >> 6, c = i & 63;             // write coalesced over k
    d[(size_t)(n0 + r) * EMBED + k0 + c] = T[r][c];
  }
}

// ---------------- GEMM  C[M][N] = A[M][1024] * Bt[N][1024]^T ----------------
// Rewritten: big-tile (BMxBN), BK=32, 512 threads (8 waves as 2x4), K/V-style
// double-buffer with prefetch-before-compute and ONE barrier per K-tile
// (attn_k's proven schedule). LDS stays < 64 KB static:
//   MODE0: 256x192, 56 KB, grid 16x16 = 256 blocks = exactly 1/CU (no tail)
//   MODE1: 128x128, 32 KB, grid 32x8  = 256 blocks
// Swizzle for 64B rows: LDS chunk c of row r holds global chunk c ^ ((r>>1)&3)
// (bijective per 8-row stripe; read hits 8 distinct 16B slots -> 2-way only).
// Accumulation order over k identical to previous kernel (same numerics).
// MODE 0 (N=3072): col<1024 -> Q (scaled QSCALE), <2048 -> K, else -> V^T scatter
// MODE 1: fp32 out [M][1024] + bias (column-indexed)
template<int MODE, int BM, int BN>
__global__ __launch_bounds__(512, 2)
void gemm_k(const unsigned short* __restrict__ A,
            const unsigned short* __restrict__ Bt,
            const float* __restrict__ b0, const float* __restrict__ b1,
            const float* __restrict__ b2,
            unsigned short* __restrict__ oQ, unsigned short* __restrict__ oK,
            unsigned short* __restrict__ oV, float* __restrict__ oF) {
  constexpr int MI = BM / 32;               // acc fragments in M per wave (wave M = BM/2)
  constexpr int NJ = BN / 64;               // acc fragments in N per wave (wave N = BN/4)
  constexpr int AG = BM / 128;              // A-stage instrs per wave (16 rows each)
  constexpr int BG = (BN / 16 + 7) / 8;     // B-stage instr rounds
  constexpr int NT = EMBED / 32;            // 32 K-tiles

  __shared__ unsigned short As[2][BM][32];
  __shared__ unsigned short Bs[2][BN][32];

  const int tid = threadIdx.x, lane = tid & 63, wave = tid >> 6;
  const int lr = lane & 15, quad = lane >> 4;
  const int wm = (wave >> 2) * (BM / 2);    // wave row origin (2 wave-rows)
  const int wn = (wave & 3) * (BN / 4);     // wave col origin (4 wave-cols)
  const int row0 = blockIdx.x * BM, col0 = blockIdx.y * BN;
  const int srow = lane >> 2, sc = lane & 3;          // stage: 16 rows x 4 chunks/instr
  const int scsw = (sc ^ ((srow >> 1) & 3)) * 8;      // pre-swizzled global chunk (stage)
  const int sw = (quad ^ ((lr >> 1) & 3)) * 8;        // swizzled LDS chunk (read)

  const f32x4 fz = {0.f, 0.f, 0.f, 0.f};
  f32x4 acc[MI][NJ];
#pragma unroll
  for (int i = 0; i < MI; ++i)
#pragma unroll
    for (int j = 0; j < NJ; ++j) acc[i][j] = fz;

  auto stage = [&](int bufi, int tt) {
#pragma unroll
    for (int g = 0; g < AG; ++g) {          // A: BM rows, 16 rows/instr/wave
      int rbase = wave * (BM / 8) + g * 16;
      gload_lds16(&A[(size_t)(row0 + rbase + srow) * EMBED + tt * 32 + scsw],
                  &As[bufi][rbase][0]);
    }
#pragma unroll
    for (int g = 0; g < BG; ++g) {          // B: BN rows, slots interleaved by wave
      int slot = wave + 8 * g;
      if (slot * 16 < BN) {
        int rbase = slot * 16;
        gload_lds16(&Bt[(size_t)(col0 + rbase + srow) * EMBED + tt * 32 + scsw],
                    &Bs[bufi][rbase][0]);
      }
    }
  };

  // prologue: stage tile 0, drain, enter loop
  stage(0, 0);
  __syncthreads();

  for (int t = 0;;) {
    const int buf = t & 1;
    // issue prefetch of tile t+1 BEFORE compute; end-of-iter barrier's vmcnt(0)
    // drain then overlaps the whole compute phase (attn_k's schedule).
    if (t + 1 < NT) stage(buf ^ 1, t + 1);

    bf16x8 af[MI], bv[NJ];
#pragma unroll
    for (int i = 0; i < MI; ++i)
      af[i] = *reinterpret_cast<const bf16x8*>(&As[buf][wm + i * 16 + lr][sw]);
#pragma unroll
    for (int j = 0; j < NJ; ++j)
      bv[j] = *reinterpret_cast<const bf16x8*>(&Bs[buf][wn + j * 16 + lr][sw]);

    __builtin_amdgcn_s_setprio(1);
#pragma unroll
    for (int i = 0; i < MI; ++i)
#pragma unroll
      for (int j = 0; j < NJ; ++j)
        acc[i][j] = __builtin_amdgcn_mfma_f32_16x16x32_bf16(af[i], bv[j],
                                                            acc[i][j], 0, 0, 0);
    __builtin_amdgcn_s_setprio(0);

    if (++t == NT) break;
    __syncthreads();   // (a) all waves done reading buf; (b) prefetch staged
  }

#pragma unroll
  for (int i = 0; i < MI; ++i) {
#pragma unroll
    for (int j = 0; j < NJ; ++j) {
      const int col = col0 + wn + j * 16 + lr;
      if (MODE == 1) {
        const float bb = b0[col];
#pragma unroll
        for (int r = 0; r < 4; ++r) {
          const int row = row0 + wm + i * 16 + quad * 4 + r;
          oF[((size_t)row << 10) + col] = acc[i][j][r] + bb;
        }
      } else {
        const int which = col >> 10, cn = col & 1023;   // uniform per 16-col group
        const float bb = (which == 0 ? b0 : which == 1 ? b1 : b2)[cn];
        const float sscale = (which == 0) ? QSCALE : 1.0f;
        const int h = cn >> 6, dd = cn & 63;
#pragma unroll
        for (int r = 0; r < 4; ++r) {
          const int row = row0 + wm + i * 16 + quad * 4 + r;
          const int b = row >> 11, ss = row & (SEQ - 1);
          const float v = (acc[i][j][r] + bb) * sscale;
          if (which == 0) {
            oQ[((((size_t)b * NHEAD + h) * SEQ + ss) << 6) + dd] = f2bf(v);
          } else if (which == 1) {
            oK[((((size_t)b * NHEAD + h) * SEQ + ss) << 6) + dd] = f2bf(v);
          } else {
            oV[(((size_t)b * NHEAD + h) * HDIM + dd) * SEQ + ss] = f2bf(v);
          }
        }
      }
    }
  }
}

// ---------------- flash attention: K/V double-buffer, ONE barrier per iter ----------------
// (unchanged from previous round)
__global__ __launch_bounds__(256, 4)
void attn_k(const unsigned short* __restrict__ Qb,   // [B][H][S][Dh], pre-scaled
            const unsigned short* __restrict__ Kb,   // [B][H][S][Dh]
            const unsigned short* __restrict__ Vt,   // [B][H][Dh][S]
            unsigned short* __restrict__ Ctx) {      // [B][S][EMBED] bf16
  __shared__ unsigned short QPs[64][64];     // Q tile, then P^T
  __shared__ unsigned short Ks[2][64][64];
  __shared__ unsigned short Vs[2][64][64];
  const int tid = threadIdx.x, lane = tid & 63, wave = tid >> 6;
  const int lr = lane & 15, quad = lane >> 4;
  const int bh = blockIdx.x, qt = blockIdx.y;
  const size_t base = (size_t)bh * SEQ * HDIM;
  const int srow = lane >> 3, sc = lane & 7;
  const int sw0 = (quad ^ (lr & 7)) * 8;
  const int sw1 = ((quad ^ 4) ^ (lr & 7)) * 8;

  // stage Q + K/V tile 0 into buffer 0
#pragma unroll
  for (int g = 0; g < 2; ++g) {
    int rbase = wave * 16 + g * 8;
    int row = rbase + srow;
    gload_lds16(&Qb[base + (size_t)(qt * 64 + row) * HDIM + ((sc ^ (row & 7)) * 8)],
                &QPs[rbase][0]);
    gload_lds16(&Kb[base + (size_t)row * HDIM + ((sc ^ (row & 7)) * 8)],
                &Ks[0][rbase][0]);
    gload_lds16(&Vt[base + (size_t)row * SEQ + ((sc ^ (row & 7)) * 8)],
                &Vs[0][rbase][0]);
  }
  __syncthreads();

  // hoist Q frags (B operand: n = q = lane&15); QPs then becomes the P^T buffer
  const bf16x8 qf0 = *reinterpret_cast<const bf16x8*>(&QPs[wave * 16 + lr][sw0]);
  const bf16x8 qf1 = *reinterpret_cast<const bf16x8*>(&QPs[wave * 16 + lr][sw1]);
  __threadfence_block();   // Q reads complete before any P write to same rows

  float l_part = 0.f;                       // per-lane partial of sum(exp2(s))
  const f32x4 fz = {0.f, 0.f, 0.f, 0.f};
  f32x4 oacc[4] = {fz, fz, fz, fz};

  constexpr int NT = SEQ / 64;
  for (int kt = 0;;) {
    const int buf = kt & 1;

    // issue async prefetch of tile kt+1 into the other buffer BEFORE compute;
    // the end-of-iter barrier's vmcnt drain overlaps this whole compute phase.
    if (kt + 1 < NT) {
#pragma unroll
      for (int g = 0; g < 2; ++g) {
        int rbase = wave * 16 + g * 8;
        int row = rbase + srow;
        gload_lds16(&Kb[base + (size_t)((kt + 1) * 64 + row) * HDIM + ((sc ^ (row & 7)) * 8)],
                    &Ks[buf ^ 1][rbase][0]);
        gload_lds16(&Vt[base + (size_t)row * SEQ + (kt + 1) * 64 + ((sc ^ (row & 7)) * 8)],
                    &Vs[buf ^ 1][rbase][0]);
      }
    }

    // S^T[key][q]: A = K rows, B = Q
    f32x4 sc4[4];
#pragma unroll
    for (int nt = 0; nt < 4; ++nt) {
      bf16x8 kf0 = *reinterpret_cast<const bf16x8*>(&Ks[buf][nt * 16 + lr][sw0]);
      bf16x8 kf1 = *reinterpret_cast<const bf16x8*>(&Ks[buf][nt * 16 + lr][sw1]);
      f32x4 a = __builtin_amdgcn_mfma_f32_16x16x32_bf16(kf0, qf0, fz, 0, 0, 0);
      sc4[nt] = __builtin_amdgcn_mfma_f32_16x16x32_bf16(kf1, qf1, a, 0, 0, 0);
    }

    // P = exp2(S) unnormalized; accumulate l partial; pack + write P^T
#pragma unroll
    for (int nt = 0; nt < 4; ++nt) {
      float p0 = __builtin_amdgcn_exp2f(sc4[nt][0]);
      float p1 = __builtin_amdgcn_exp2f(sc4[nt][1]);
      float p2 = __builtin_amdgcn_exp2f(sc4[nt][2]);
      float p3 = __builtin_amdgcn_exp2f(sc4[nt][3]);
      l_part += (p0 + p1) + (p2 + p3);
      const int pc = (nt * 2 + (quad >> 1)) ^ (lr & 7);
      *reinterpret_cast<uint2*>(&QPs[wave * 16 + lr][pc * 8 + (quad & 1) * 4]) =
          make_uint2(pkbf(p0, p1), pkbf(p2, p3));
    }

    __threadfence_block();   // order P writes before same-wave reads

    const bf16x8 pa0 = *reinterpret_cast<const bf16x8*>(&QPs[wave * 16 + lr][sw0]);
    const bf16x8 pa1 = *reinterpret_cast<const bf16x8*>(&QPs[wave * 16 + lr][sw1]);
#pragma unroll
    for (int d = 0; d < 4; ++d) {
      bf16x8 vb0 = *reinterpret_cast<const bf16x8*>(&Vs[buf][d * 16 + lr][sw0]);
      bf16x8 vb1 = *reinterpret_cast<const bf16x8*>(&Vs[buf][d * 16 + lr][sw1]);
      oacc[d] = __builtin_amdgcn_mfma_f32_16x16x32_bf16(pa0, vb0, oacc[d], 0, 0, 0);
      oacc[d] = __builtin_amdgcn_mfma_f32_16x16x32_bf16(pa1, vb1, oacc[d], 0, 0, 0);
    }

    if (++kt == NT) break;
    // single barrier: (a) all waves done reading buf -> safe to overwrite next
    // iter; (b) drains prefetch vmcnt -> buf^1 fully staged for next iter.
    __syncthreads();
  }

  // finalize l: quads covered disjoint keys
  l_part += __shfl_xor(l_part, 16);
  l_part += __shfl_xor(l_part, 32);

  const int b = bh >> 4, h = bh & 15;
  float linv[4];
#pragma unroll
  for (int r = 0; r < 4; ++r) linv[r] = 1.0f / __shfl(l_part, quad * 4 + r);
#pragma unroll
  for (int d = 0; d < 4; ++d)
#pragma unroll
    for (int r = 0; r < 4; ++r) {
      const int q = qt * 64 + wave * 16 + quad * 4 + r;
      Ctx[(((size_t)b * SEQ + q) << 10) + h * 64 + d * 16 + lr] =
          f2bf(oacc[d][r] * linv[r]);
    }
}

// ---------------- launch ----------------
extern "C" void kernel_launch(void* const* d_in, const int* in_sizes, int n_in,
                              void* d_out, int out_size, void* d_ws, size_t ws_size,
                              hipStream_t stream) {
  const float* X  = (const float*)d_in[0];
  const float* Wq = (const float*)d_in[1];
  const float* bq = (const float*)d_in[2];
  const float* Wk = (const float*)d_in[3];
  const float* bk = (const float*)d_in[4];
  const float* Wv = (const float*)d_in[5];
  const float* bv = (const float*)d_in[6];
  const float* Wo = (const float*)d_in[7];
  const float* bo = (const float*)d_in[8];

  unsigned short* ws = (unsigned short*)d_ws;
  const size_t M1 = (size_t)1024 * 1024;
  unsigned short* Xbf = ws;                 // 4M shorts
  unsigned short* WqT = ws + 4 * M1;        // weights n-major (q,k,v contiguous for fused B)
  unsigned short* WkT = ws + 5 * M1;
  unsigned short* WvT = ws + 6 * M1;
  unsigned short* WoT = ws + 7 * M1;
  unsigned short* Qb  = ws + 8 * M1;
  unsigned short* Kb  = ws + 12 * M1;
  unsigned short* Vt  = ws + 16 * M1;
  unsigned short* Ctx = ws + 20 * M1;       // 48 MB total

  // prep: cast X (4096 blocks) + 4 weight transposes (1024 blocks)
  prep_k<<<5120, 256, 0, stream>>>(X, Xbf, Wq, Wk, Wv, Wo, WqT, WkT, WvT, WoT);

  // fused QKV projection: Bt = [WqT;WkT;WvT], N=3072
  // 256x192 tile, 512 thr, dbuf BK=32: grid 16x16 = 256 blocks = 1/CU, no tail
  gemm_k<0, 256, 192><<<dim3(MTOK / 256, 3072 / 192), 512, 0, stream>>>(
      Xbf, WqT, bq, bk, bv, Qb, Kb, Vt, nullptr);

  // grid x = bh for XCD-pinned K/V L2 residency
  attn_k<<<dim3(BATCH * NHEAD, SEQ / 64), 256, 0, stream>>>(Qb, Kb, Vt, Ctx);

  // output projection: 128x128 tile, 512 thr, dbuf BK=32: grid 32x8 = 256 blocks
  gemm_k<1, 128, 128><<<dim3(MTOK / 128, EMBED / 128), 512, 0, stream>>>(
      Ctx, WoT, bo, nullptr, nullptr, nullptr, nullptr, nullptr, (float*)d_out);
}

// Round 2
// 198.043 us; speedup vs baseline: 1.1104x; 1.1104x over previous
//
#include <hip/hip_runtime.h>

#define EMBED 1024
#define NHEAD 16
#define HDIM  64
#define BATCH 2
#define SEQ   2048
#define MTOK  (BATCH * SEQ)   // 4096 tokens
#define QSCALE 0.1803368801f  // (1/sqrt(64)) * log2(e): softmax done in base 2

typedef __bf16 bf16x8 __attribute__((ext_vector_type(8)));
typedef float  f32x4  __attribute__((ext_vector_type(4)));

// round-half-up f32->bf16 (bias <= 2^-25, well under harness threshold)
__device__ __forceinline__ unsigned short f2bf(float f) {
  return (unsigned short)((__float_as_uint(f) + 0x8000u) >> 16);
}
// pack two f32 -> bf16x2 in one v_perm
__device__ __forceinline__ unsigned int pkbf(float a, float b) {
  unsigned int ua = __float_as_uint(a) + 0x8000u;
  unsigned int ub = __float_as_uint(b) + 0x8000u;
  return __builtin_amdgcn_perm(ub, ua, 0x07060302u);
}

// async global->LDS, 16B/lane; LDS dest = wave-uniform base + lane*16
__device__ __forceinline__ void gload_lds16(const unsigned short* g, unsigned short* l) {
  __builtin_amdgcn_global_load_lds((__attribute__((address_space(1))) void*)g,
                                   (__attribute__((address_space(3))) void*)l, 16, 0, 0);
}

// ---------------- prep: cast X -> bf16 (blocks 0..4095) + 4 weight transpose-casts ----------
__global__ __launch_bounds__(256)
void prep_k(const float* __restrict__ X, unsigned short* __restrict__ Xbf,
            const float* __restrict__ w0, const float* __restrict__ w1,
            const float* __restrict__ w2, const float* __restrict__ w3,
            unsigned short* __restrict__ t0, unsigned short* __restrict__ t1,
            unsigned short* __restrict__ t2, unsigned short* __restrict__ t3) {
  const int id = blockIdx.x;
  if (id < 4096) {                          // cast: 1M uint2 = 4M floats
    int i = id * 256 + threadIdx.x;
    float4 f = reinterpret_cast<const float4*>(X)[i];
    reinterpret_cast<uint2*>(Xbf)[i] = make_uint2(pkbf(f.x, f.y), pkbf(f.z, f.w));
    return;
  }
  const int t = id - 4096;                  // 0..1023: 4 weights x 256 tiles
  const float* s; unsigned short* d;
  switch (t >> 8) {
    case 0: s = w0; d = t0; break;
    case 1: s = w1; d = t1; break;
    case 2: s = w2; d = t2; break;
    default: s = w3; d = t3; break;
  }
  const int tt = t & 255;
  const int k0 = (tt >> 4) * 64, n0 = (tt & 15) * 64;
  __shared__ unsigned short T[64][65];
  for (int i = threadIdx.x; i < 4096; i += 256) {
    int r = i >> 6, c = i & 63;             // read coalesced over n
    T[c][r] = f2bf(s[(size_t)(k0 + r) * EMBED + n0 + c]);
  }
  __syncthreads();
  for (int i = threadIdx.x; i < 4096; i += 256) {
    int r = i >> 6, c = i & 63;             // write coalesced over k
    d[(size_t)(n0 + r) * EMBED + k0 + c] = T[r][c];
  }
}

// ---------------- GEMM  C[M][N] = A[M][1024] * Bt[N][1024]^T ----------------
// Round-2: r9 geometry (BMx128 tile, 256 thr / 4 waves as 2x2, no launch_bounds)
// with attn_k's 2-phase schedule: BK=32 double-buffer, prefetch of tile t+1
// issued BEFORE computing tile t, ONE barrier per K-tile. Same barrier count
// as the old BK=64 2-barrier loop (32), same LDS footprint class:
//   MODE0 (BM=128): 32 KB LDS, grid 32x24 = 768 blocks (~3-4 blocks/CU)
//   MODE1 (BM=64):  24 KB LDS, grid 64x8  = 512 blocks
// Swizzle: round-1's measured-conflict-free pattern for 64B rows
// (chunk = quad ^ ((lr>>1)&3); stage pre-swizzles the global source chunk).
// Accumulation order over k identical to previous rounds (same numerics).
// MODE 0 (N=3072): col<1024 -> Q (scaled QSCALE), <2048 -> K, else -> V^T scatter
// MODE 1: fp32 out [M][1024] + bias (column-indexed)
template<int MODE, int BM>
__global__ void gemm_k(const unsigned short* __restrict__ A,
                       const unsigned short* __restrict__ Bt,
                       const float* __restrict__ b0, const float* __restrict__ b1,
                       const float* __restrict__ b2,
                       unsigned short* __restrict__ oQ, unsigned short* __restrict__ oK,
                       unsigned short* __restrict__ oV, float* __restrict__ oF) {
  constexpr int MI = BM / 32;               // 4 (MODE0) or 2 (MODE1)
  constexpr int NT = EMBED / 32;            // 32 K-tiles

  __shared__ unsigned short As[2][BM][32];
  __shared__ unsigned short Bs[2][128][32];

  const int tid = threadIdx.x, lane = tid & 63, wave = tid >> 6;
  const int lr = lane & 15, quad = lane >> 4;
  const int wm = (wave >> 1) * (BM / 2), wn = (wave & 1) * 64;
  const int row0 = blockIdx.x * BM, col0 = blockIdx.y * 128;   // row-fastest
  const int srow = lane >> 2, sc = lane & 3;          // stage: 16 rows x 4 chunks/instr
  const int scsw = (sc ^ ((srow >> 1) & 3)) * 8;      // pre-swizzled global chunk (stage)
  const int sw = (quad ^ ((lr >> 1) & 3)) * 8;        // swizzled LDS chunk (read)

  const f32x4 fz = {0.f, 0.f, 0.f, 0.f};
  f32x4 acc[MI][4];
#pragma unroll
  for (int i = 0; i < MI; ++i)
#pragma unroll
    for (int j = 0; j < 4; ++j) acc[i][j] = fz;

  auto stage = [&](int bufi, int tt) {
#pragma unroll
    for (int g = 0; g < BM / 64; ++g) {     // A: BM rows, 16 rows/instr/wave
      int rbase = wave * (BM / 4) + g * 16;
      gload_lds16(&A[(size_t)(row0 + rbase + srow) * EMBED + tt * 32 + scsw],
                  &As[bufi][rbase][0]);
    }
#pragma unroll
    for (int g = 0; g < 2; ++g) {           // B: 128 rows, 2 instrs/wave
      int rbase = wave * 32 + g * 16;
      gload_lds16(&Bt[(size_t)(col0 + rbase + srow) * EMBED + tt * 32 + scsw],
                  &Bs[bufi][rbase][0]);
    }
  };

  // prologue: stage tile 0, drain, enter loop
  stage(0, 0);
  __syncthreads();

  for (int t = 0;;) {
    const int buf = t & 1;
    // issue prefetch of tile t+1 BEFORE compute; end-of-iter barrier's vmcnt(0)
    // drain then overlaps the whole compute phase (attn_k's schedule).
    if (t + 1 < NT) stage(buf ^ 1, t + 1);

    bf16x8 af[MI], bv[4];
#pragma unroll
    for (int i = 0; i < MI; ++i)
      af[i] = *reinterpret_cast<const bf16x8*>(&As[buf][wm + i * 16 + lr][sw]);
#pragma unroll
    for (int j = 0; j < 4; ++j)
      bv[j] = *reinterpret_cast<const bf16x8*>(&Bs[buf][wn + j * 16 + lr][sw]);

    __builtin_amdgcn_s_setprio(1);
#pragma unroll
    for (int i = 0; i < MI; ++i)
#pragma unroll
      for (int j = 0; j < 4; ++j)
        acc[i][j] = __builtin_amdgcn_mfma_f32_16x16x32_bf16(af[i], bv[j],
                                                            acc[i][j], 0, 0, 0);
    __builtin_amdgcn_s_setprio(0);

    if (++t == NT) break;
    __syncthreads();   // (a) all waves done reading buf; (b) prefetch staged
  }

#pragma unroll
  for (int i = 0; i < MI; ++i) {
#pragma unroll
    for (int j = 0; j < 4; ++j) {
      const int col = col0 + wn + j * 16 + lr;
      if (MODE == 1) {
        const float bb = b0[col];
#pragma unroll
        for (int r = 0; r < 4; ++r) {
          const int row = row0 + wm + i * 16 + quad * 4 + r;
          oF[((size_t)row << 10) + col] = acc[i][j][r] + bb;
        }
      } else {
        const int which = col >> 10, cn = col & 1023;   // wave-uniform
        const float bb = (which == 0 ? b0 : which == 1 ? b1 : b2)[cn];
        const float sscale = (which == 0) ? QSCALE : 1.0f;
        const int h = cn >> 6, dd = cn & 63;
#pragma unroll
        for (int r = 0; r < 4; ++r) {
          const int row = row0 + wm + i * 16 + quad * 4 + r;
          const int b = row >> 11, ss = row & (SEQ - 1);
          const float v = (acc[i][j][r] + bb) * sscale;
          if (which == 0) {
            oQ[((((size_t)b * NHEAD + h) * SEQ + ss) << 6) + dd] = f2bf(v);
          } else if (which == 1) {
            oK[((((size_t)b * NHEAD + h) * SEQ + ss) << 6) + dd] = f2bf(v);
          } else {
            oV[(((size_t)b * NHEAD + h) * HDIM + dd) * SEQ + ss] = f2bf(v);
          }
        }
      }
    }
  }
}

// ---------------- flash attention: K/V double-buffer, ONE barrier per iter ----------------
// (unchanged — known-good 59.7 us; diagnosed LDS-pipe-bound, separate experiment)
__global__ __launch_bounds__(256, 4)
void attn_k(const unsigned short* __restrict__ Qb,   // [B][H][S][Dh], pre-scaled
            const unsigned short* __restrict__ Kb,   // [B][H][S][Dh]
            const unsigned short* __restrict__ Vt,   // [B][H][Dh][S]
            unsigned short* __restrict__ Ctx) {      // [B][S][EMBED] bf16
  __shared__ unsigned short QPs[64][64];     // Q tile, then P^T
  __shared__ unsigned short Ks[2][64][64];
  __shared__ unsigned short Vs[2][64][64];
  const int tid = threadIdx.x, lane = tid & 63, wave = tid >> 6;
  const int lr = lane & 15, quad = lane >> 4;
  const int bh = blockIdx.x, qt = blockIdx.y;
  const size_t base = (size_t)bh * SEQ * HDIM;
  const int srow = lane >> 3, sc = lane & 7;
  const int sw0 = (quad ^ (lr & 7)) * 8;
  const int sw1 = ((quad ^ 4) ^ (lr & 7)) * 8;

  // stage Q + K/V tile 0 into buffer 0
#pragma unroll
  for (int g = 0; g < 2; ++g) {
    int rbase = wave * 16 + g * 8;
    int row = rbase + srow;
    gload_lds16(&Qb[base + (size_t)(qt * 64 + row) * HDIM + ((sc ^ (row & 7)) * 8)],
                &QPs[rbase][0]);
    gload_lds16(&Kb[base + (size_t)row * HDIM + ((sc ^ (row & 7)) * 8)],
                &Ks[0][rbase][0]);
    gload_lds16(&Vt[base + (size_t)row * SEQ + ((sc ^ (row & 7)) * 8)],
                &Vs[0][rbase][0]);
  }
  __syncthreads();

  // hoist Q frags (B operand: n = q = lane&15); QPs then becomes the P^T buffer
  const bf16x8 qf0 = *reinterpret_cast<const bf16x8*>(&QPs[wave * 16 + lr][sw0]);
  const bf16x8 qf1 = *reinterpret_cast<const bf16x8*>(&QPs[wave * 16 + lr][sw1]);
  __threadfence_block();   // Q reads complete before any P write to same rows

  float l_part = 0.f;                       // per-lane partial of sum(exp2(s))
  const f32x4 fz = {0.f, 0.f, 0.f, 0.f};
  f32x4 oacc[4] = {fz, fz, fz, fz};

  constexpr int NT = SEQ / 64;
  for (int kt = 0;;) {
    const int buf = kt & 1;

    // issue async prefetch of tile kt+1 into the other buffer BEFORE compute;
    // the end-of-iter barrier's vmcnt drain overlaps this whole compute phase.
    if (kt + 1 < NT) {
#pragma unroll
      for (int g = 0; g < 2; ++g) {
        int rbase = wave * 16 + g * 8;
        int row = rbase + srow;
        gload_lds16(&Kb[base + (size_t)((kt + 1) * 64 + row) * HDIM + ((sc ^ (row & 7)) * 8)],
                    &Ks[buf ^ 1][rbase][0]);
        gload_lds16(&Vt[base + (size_t)row * SEQ + (kt + 1) * 64 + ((sc ^ (row & 7)) * 8)],
                    &Vs[buf ^ 1][rbase][0]);
      }
    }

    // S^T[key][q]: A = K rows, B = Q
    f32x4 sc4[4];
#pragma unroll
    for (int nt = 0; nt < 4; ++nt) {
      bf16x8 kf0 = *reinterpret_cast<const bf16x8*>(&Ks[buf][nt * 16 + lr][sw0]);
      bf16x8 kf1 = *reinterpret_cast<const bf16x8*>(&Ks[buf][nt * 16 + lr][sw1]);
      f32x4 a = __builtin_amdgcn_mfma_f32_16x16x32_bf16(kf0, qf0, fz, 0, 0, 0);
      sc4[nt] = __builtin_amdgcn_mfma_f32_16x16x32_bf16(kf1, qf1, a, 0, 0, 0);
    }

    // P = exp2(S) unnormalized; accumulate l partial; pack + write P^T
#pragma unroll
    for (int nt = 0; nt < 4; ++nt) {
      float p0 = __builtin_amdgcn_exp2f(sc4[nt][0]);
      float p1 = __builtin_amdgcn_exp2f(sc4[nt][1]);
      float p2 = __builtin_amdgcn_exp2f(sc4[nt][2]);
      float p3 = __builtin_amdgcn_exp2f(sc4[nt][3]);
      l_part += (p0 + p1) + (p2 + p3);
      const int pc = (nt * 2 + (quad >> 1)) ^ (lr & 7);
      *reinterpret_cast<uint2*>(&QPs[wave * 16 + lr][pc * 8 + (quad & 1) * 4]) =
          make_uint2(pkbf(p0, p1), pkbf(p2, p3));
    }

    __threadfence_block();   // order P writes before same-wave reads

    const bf16x8 pa0 = *reinterpret_cast<const bf16x8*>(&QPs[wave * 16 + lr][sw0]);
    const bf16x8 pa1 = *reinterpret_cast<const bf16x8*>(&QPs[wave * 16 + lr][sw1]);
#pragma unroll
    for (int d = 0; d < 4; ++d) {
      bf16x8 vb0 = *reinterpret_cast<const bf16x8*>(&Vs[buf][d * 16 + lr][sw0]);
      bf16x8 vb1 = *reinterpret_cast<const bf16x8*>(&Vs[buf][d * 16 + lr][sw1]);
      oacc[d] = __builtin_amdgcn_mfma_f32_16x16x32_bf16(pa0, vb0, oacc[d], 0, 0, 0);
      oacc[d] = __builtin_amdgcn_mfma_f32_16x16x32_bf16(pa1, vb1, oacc[d], 0, 0, 0);
    }

    if (++kt == NT) break;
    // single barrier: (a) all waves done reading buf -> safe to overwrite next
    // iter; (b) drains prefetch vmcnt -> buf^1 fully staged for next iter.
    __syncthreads();
  }

  // finalize l: quads covered disjoint keys
  l_part += __shfl_xor(l_part, 16);
  l_part += __shfl_xor(l_part, 32);

  const int b = bh >> 4, h = bh & 15;
  float linv[4];
#pragma unroll
  for (int r = 0; r < 4; ++r) linv[r] = 1.0f / __shfl(l_part, quad * 4 + r);
#pragma unroll
  for (int d = 0; d < 4; ++d)
#pragma unroll
    for (int r = 0; r < 4; ++r) {
      const int q = qt * 64 + wave * 16 + quad * 4 + r;
      Ctx[(((size_t)b * SEQ + q) << 10) + h * 64 + d * 16 + lr] =
          f2bf(oacc[d][r] * linv[r]);
    }
}

// ---------------- launch ----------------
extern "C" void kernel_launch(void* const* d_in, const int* in_sizes, int n_in,
                              void* d_out, int out_size, void* d_ws, size_t ws_size,
                              hipStream_t stream) {
  const float* X  = (const float*)d_in[0];
  const float* Wq = (const float*)d_in[1];
  const float* bq = (const float*)d_in[2];
  const float* Wk = (const float*)d_in[3];
  const float* bk = (const float*)d_in[4];
  const float* Wv = (const float*)d_in[5];
  const float* bv = (const float*)d_in[6];
  const float* Wo = (const float*)d_in[7];
  const float* bo = (const float*)d_in[8];

  unsigned short* ws = (unsigned short*)d_ws;
  const size_t M1 = (size_t)1024 * 1024;
  unsigned short* Xbf = ws;                 // 4M shorts
  unsigned short* WqT = ws + 4 * M1;        // weights n-major (q,k,v contiguous for fused B)
  unsigned short* WkT = ws + 5 * M1;
  unsigned short* WvT = ws + 6 * M1;
  unsigned short* WoT = ws + 7 * M1;
  unsigned short* Qb  = ws + 8 * M1;
  unsigned short* Kb  = ws + 12 * M1;
  unsigned short* Vt  = ws + 16 * M1;
  unsigned short* Ctx = ws + 20 * M1;       // 48 MB total

  // prep: cast X (4096 blocks) + 4 weight transposes (1024 blocks)
  prep_k<<<5120, 256, 0, stream>>>(X, Xbf, Wq, Wk, Wv, Wo, WqT, WkT, WvT, WoT);

  // fused QKV projection: Bt = [WqT;WkT;WvT], N=3072; 128x128, 2-phase dbuf
  gemm_k<0, 128><<<dim3(MTOK / 128, 3072 / 128), 256, 0, stream>>>(
      Xbf, WqT, bq, bk, bv, Qb, Kb, Vt, nullptr);

  // grid x = bh for XCD-pinned K/V L2 residency
  attn_k<<<dim3(BATCH * NHEAD, SEQ / 64), 256, 0, stream>>>(Qb, Kb, Vt, Ctx);

  // output projection: 64x128, 2-phase dbuf
  gemm_k<1, 64><<<dim3(MTOK / 64, EMBED / 128), 256, 0, stream>>>(
      Ctx, WoT, bo, nullptr, nullptr, nullptr, nullptr, nullptr, (float*)d_out);
}

// Round 3
// 189.131 us; speedup vs baseline: 1.1627x; 1.0471x over previous
//
#include <hip/hip_runtime.h>

#define EMBED 1024
#define NHEAD 16
#define HDIM  64
#define BATCH 2
#define SEQ   2048
#define MTOK  (BATCH * SEQ)   // 4096 tokens
#define QSCALE 0.1803368801f  // (1/sqrt(64)) * log2(e): softmax done in base 2

typedef __bf16 bf16x8 __attribute__((ext_vector_type(8)));
typedef float  f32x4  __attribute__((ext_vector_type(4)));

// round-half-up f32->bf16 (bias <= 2^-25, well under harness threshold)
__device__ __forceinline__ unsigned short f2bf(float f) {
  return (unsigned short)((__float_as_uint(f) + 0x8000u) >> 16);
}
// pack two f32 -> bf16x2 in one v_perm
__device__ __forceinline__ unsigned int pkbf(float a, float b) {
  unsigned int ua = __float_as_uint(a) + 0x8000u;
  unsigned int ub = __float_as_uint(b) + 0x8000u;
  return __builtin_amdgcn_perm(ub, ua, 0x07060302u);
}

// async global->LDS, 16B/lane; LDS dest = wave-uniform base + lane*16
__device__ __forceinline__ void gload_lds16(const unsigned short* g, unsigned short* l) {
  __builtin_amdgcn_global_load_lds((__attribute__((address_space(1))) void*)g,
                                   (__attribute__((address_space(3))) void*)l, 16, 0, 0);
}

// ---------------- prep: cast X -> bf16 (blocks 0..4095) + 4 weight transpose-casts ----------
__global__ __launch_bounds__(256)
void prep_k(const float* __restrict__ X, unsigned short* __restrict__ Xbf,
            const float* __restrict__ w0, const float* __restrict__ w1,
            const float* __restrict__ w2, const float* __restrict__ w3,
            unsigned short* __restrict__ t0, unsigned short* __restrict__ t1,
            unsigned short* __restrict__ t2, unsigned short* __restrict__ t3) {
  const int id = blockIdx.x;
  if (id < 4096) {                          // cast: 1M uint2 = 4M floats
    int i = id * 256 + threadIdx.x;
    float4 f = reinterpret_cast<const float4*>(X)[i];
    reinterpret_cast<uint2*>(Xbf)[i] = make_uint2(pkbf(f.x, f.y), pkbf(f.z, f.w));
    return;
  }
  const int t = id - 4096;                  // 0..1023: 4 weights x 256 tiles
  const float* s; unsigned short* d;
  switch (t >> 8) {
    case 0: s = w0; d = t0; break;
    case 1: s = w1; d = t1; break;
    case 2: s = w2; d = t2; break;
    default: s = w3; d = t3; break;
  }
  const int tt = t & 255;
  const int k0 = (tt >> 4) * 64, n0 = (tt & 15) * 64;
  __shared__ unsigned short T[64][65];
  for (int i = threadIdx.x; i < 4096; i += 256) {
    int r = i >> 6, c = i & 63;             // read coalesced over n
    T[c][r] = f2bf(s[(size_t)(k0 + r) * EMBED + n0 + c]);
  }
  __syncthreads();
  for (int i = threadIdx.x; i < 4096; i += 256) {
    int r = i >> 6, c = i & 63;             // write coalesced over k
    d[(size_t)(n0 + r) * EMBED + k0 + c] = T[r][c];
  }
}

// ---------------- GEMM  C[M][N] = A[M][1024] * Bt[N][1024]^T ----------------
// Round-3: T4 counted-vmcnt pipeline. 3 LDS buffers, prefetch distance 2,
// ONE raw s_barrier per K-tile, vmcnt(LPT) waits for ONLY the tile about to
// be consumed (2 tiles stay in flight across the barrier - never drain to 0
// in the main loop; the last iteration peels to vmcnt(0)).
// Race-freedom: stage(t+2) is issued AFTER compute(t); the buffer it
// overwrites ((t+2)%3) was last read at iter t-1, and all waves passed the
// iter-t barrier after finishing those reads.
//   MODE0 (BM=128): 48 KB LDS, grid 32x24 = 768 blocks -> 3 blocks/CU
//   MODE1 (BM=64):  36 KB LDS, grid 64x8  = 512 blocks -> 2 blocks/CU
// Swizzle: round-1's measured-conflict-free pattern for 64B rows.
// Accumulation order over k identical to previous rounds (same numerics).
template<int MODE, int BM>
__global__ void gemm_k(const unsigned short* __restrict__ A,
                       const unsigned short* __restrict__ Bt,
                       const float* __restrict__ b0, const float* __restrict__ b1,
                       const float* __restrict__ b2,
                       unsigned short* __restrict__ oQ, unsigned short* __restrict__ oK,
                       unsigned short* __restrict__ oV, float* __restrict__ oF) {
  constexpr int MI = BM / 32;               // 4 (MODE0) or 2 (MODE1)
  constexpr int NT = EMBED / 32;            // 32 K-tiles of BK=32
  constexpr int LPT = BM / 64 + 2;          // gloads/wave/tile: A(BM/64) + B(2)

  __shared__ unsigned short As[3][BM][32];
  __shared__ unsigned short Bs[3][128][32];

  const int tid = threadIdx.x, lane = tid & 63, wave = tid >> 6;
  const int lr = lane & 15, quad = lane >> 4;
  const int wm = (wave >> 1) * (BM / 2), wn = (wave & 1) * 64;
  const int row0 = blockIdx.x * BM, col0 = blockIdx.y * 128;   // row-fastest
  const int srow = lane >> 2, sc = lane & 3;          // stage: 16 rows x 4 chunks/instr
  const int scsw = (sc ^ ((srow >> 1) & 3)) * 8;      // pre-swizzled global chunk (stage)
  const int sw = (quad ^ ((lr >> 1) & 3)) * 8;        // swizzled LDS chunk (read)

  const f32x4 fz = {0.f, 0.f, 0.f, 0.f};
  f32x4 acc[MI][4];
#pragma unroll
  for (int i = 0; i < MI; ++i)
#pragma unroll
    for (int j = 0; j < 4; ++j) acc[i][j] = fz;

  auto stage = [&](int bufi, int tt) {
#pragma unroll
    for (int g = 0; g < BM / 64; ++g) {     // A: BM rows, 16 rows/instr/wave
      int rbase = wave * (BM / 4) + g * 16;
      gload_lds16(&A[(size_t)(row0 + rbase + srow) * EMBED + tt * 32 + scsw],
                  &As[bufi][rbase][0]);
    }
#pragma unroll
    for (int g = 0; g < 2; ++g) {           // B: 128 rows, 2 instrs/wave
      int rbase = wave * 32 + g * 16;
      gload_lds16(&Bt[(size_t)(col0 + rbase + srow) * EMBED + tt * 32 + scsw],
                  &Bs[bufi][rbase][0]);
    }
  };

  // prologue: 2 tiles in flight before first wait
  stage(0, 0);
  stage(1, 1);

  int buf = 0, sb = 2;
  for (int t = 0; t < NT; ++t) {
    // wait for ONLY the tile about to be consumed; keep the rest in flight.
    if (t < NT - 1)
      asm volatile("s_waitcnt vmcnt(%0)" :: "n"(LPT) : "memory");
    else
      asm volatile("s_waitcnt vmcnt(0)" ::: "memory");
    __builtin_amdgcn_s_barrier();           // all waves' tile-t loads landed

    bf16x8 af[MI], bv[4];
#pragma unroll
    for (int i = 0; i < MI; ++i)
      af[i] = *reinterpret_cast<const bf16x8*>(&As[buf][wm + i * 16 + lr][sw]);
#pragma unroll
    for (int j = 0; j < 4; ++j)
      bv[j] = *reinterpret_cast<const bf16x8*>(&Bs[buf][wn + j * 16 + lr][sw]);

    __builtin_amdgcn_s_setprio(1);
#pragma unroll
    for (int i = 0; i < MI; ++i)
#pragma unroll
      for (int j = 0; j < 4; ++j)
        acc[i][j] = __builtin_amdgcn_mfma_f32_16x16x32_bf16(af[i], bv[j],
                                                            acc[i][j], 0, 0, 0);
    __builtin_amdgcn_s_setprio(0);

    if (t + 2 < NT) stage(sb, t + 2);       // overwrites buffer read at t-1
    buf = (buf == 2) ? 0 : buf + 1;
    sb  = (sb  == 2) ? 0 : sb  + 1;
  }

#pragma unroll
  for (int i = 0; i < MI; ++i) {
#pragma unroll
    for (int j = 0; j < 4; ++j) {
      const int col = col0 + wn + j * 16 + lr;
      if (MODE == 1) {
        const float bb = b0[col];
#pragma unroll
        for (int r = 0; r < 4; ++r) {
          const int row = row0 + wm + i * 16 + quad * 4 + r;
          oF[((size_t)row << 10) + col] = acc[i][j][r] + bb;
        }
      } else {
        const int which = col >> 10, cn = col & 1023;   // wave-uniform
        const float bb = (which == 0 ? b0 : which == 1 ? b1 : b2)[cn];
        const float sscale = (which == 0) ? QSCALE : 1.0f;
        const int h = cn >> 6, dd = cn & 63;
#pragma unroll
        for (int r = 0; r < 4; ++r) {
          const int row = row0 + wm + i * 16 + quad * 4 + r;
          const int b = row >> 11, ss = row & (SEQ - 1);
          const float v = (acc[i][j][r] + bb) * sscale;
          if (which == 0) {
            oQ[((((size_t)b * NHEAD + h) * SEQ + ss) << 6) + dd] = f2bf(v);
          } else if (which == 1) {
            oK[((((size_t)b * NHEAD + h) * SEQ + ss) << 6) + dd] = f2bf(v);
          } else {
            oV[(((size_t)b * NHEAD + h) * HDIM + dd) * SEQ + ss] = f2bf(v);
          }
        }
      }
    }
  }
}

// ---------------- flash attention: QBLK=128, 4 waves x 32 q-rows ----------------
// Round-3: each wave owns 32 q (2 groups of 16) instead of 16 -> the per-iter
// K/V LDS reads (the measured bottleneck: ~123K LDS-cyc/CU = the 59.7us) are
// amortized over 2x the q-rows. LDS = 16K(QP)+16K(K x2)+16K(V x2) = 48 KB;
// grid 32 bh x 16 qt = 512 blocks -> 2/CU (XCD pinning kept: 32 % 8 == 0).
// Same schedule as before: prefetch-before-compute, one barrier per iter.
// Per-q numerics identical to the QBLK=64 version.
__global__ __launch_bounds__(256, 2)
void attn_k(const unsigned short* __restrict__ Qb,   // [B][H][S][Dh], pre-scaled
            const unsigned short* __restrict__ Kb,   // [B][H][S][Dh]
            const unsigned short* __restrict__ Vt,   // [B][H][Dh][S]
            unsigned short* __restrict__ Ctx) {      // [B][S][EMBED] bf16
  __shared__ unsigned short QPs[128][64];    // Q tile (128 q), then P [q][k]
  __shared__ unsigned short Ks[2][64][64];
  __shared__ unsigned short Vs[2][64][64];
  const int tid = threadIdx.x, lane = tid & 63, wave = tid >> 6;
  const int lr = lane & 15, quad = lane >> 4;
  const int bh = blockIdx.x, qt = blockIdx.y;
  const size_t base = (size_t)bh * SEQ * HDIM;
  const int srow = lane >> 3, sc = lane & 7;
  const int sw0 = (quad ^ (lr & 7)) * 8;
  const int sw1 = ((quad ^ 4) ^ (lr & 7)) * 8;

  // stage Q (128 rows) + K/V tile 0 into buffer 0
#pragma unroll
  for (int g = 0; g < 4; ++g) {
    int rbase = wave * 32 + g * 8;
    int row = rbase + srow;
    gload_lds16(&Qb[base + (size_t)(qt * 128 + row) * HDIM + ((sc ^ (row & 7)) * 8)],
                &QPs[rbase][0]);
  }
#pragma unroll
  for (int g = 0; g < 2; ++g) {
    int rbase = wave * 16 + g * 8;
    int row = rbase + srow;
    gload_lds16(&Kb[base + (size_t)row * HDIM + ((sc ^ (row & 7)) * 8)],
                &Ks[0][rbase][0]);
    gload_lds16(&Vt[base + (size_t)row * SEQ + ((sc ^ (row & 7)) * 8)],
                &Vs[0][rbase][0]);
  }
  __syncthreads();

  // hoist Q frags (B operand: n = q = lane&15); QPs then becomes the P buffer
  bf16x8 qf[2][2];
#pragma unroll
  for (int g = 0; g < 2; ++g) {
    qf[g][0] = *reinterpret_cast<const bf16x8*>(&QPs[wave * 32 + g * 16 + lr][sw0]);
    qf[g][1] = *reinterpret_cast<const bf16x8*>(&QPs[wave * 32 + g * 16 + lr][sw1]);
  }
  __threadfence_block();   // Q reads complete before any P write to same rows

  float l_part[2] = {0.f, 0.f};             // per-lane partial of sum(exp2(s))
  const f32x4 fz = {0.f, 0.f, 0.f, 0.f};
  f32x4 oacc[2][4];
#pragma unroll
  for (int g = 0; g < 2; ++g)
#pragma unroll
    for (int d = 0; d < 4; ++d) oacc[g][d] = fz;

  constexpr int NT = SEQ / 64;
  for (int kt = 0;;) {
    const int buf = kt & 1;

    // issue async prefetch of tile kt+1 into the other buffer BEFORE compute;
    // the end-of-iter barrier's vmcnt drain overlaps this whole compute phase.
    if (kt + 1 < NT) {
#pragma unroll
      for (int g = 0; g < 2; ++g) {
        int rbase = wave * 16 + g * 8;
        int row = rbase + srow;
        gload_lds16(&Kb[base + (size_t)((kt + 1) * 64 + row) * HDIM + ((sc ^ (row & 7)) * 8)],
                    &Ks[buf ^ 1][rbase][0]);
        gload_lds16(&Vt[base + (size_t)row * SEQ + (kt + 1) * 64 + ((sc ^ (row & 7)) * 8)],
                    &Vs[buf ^ 1][rbase][0]);
      }
    }

    // S^T[key][q]: A = K rows, B = Q; K frags reused for both q-groups
    f32x4 sc4[2][4];
#pragma unroll
    for (int nt = 0; nt < 4; ++nt) {
      bf16x8 kf0 = *reinterpret_cast<const bf16x8*>(&Ks[buf][nt * 16 + lr][sw0]);
      bf16x8 kf1 = *reinterpret_cast<const bf16x8*>(&Ks[buf][nt * 16 + lr][sw1]);
#pragma unroll
      for (int g = 0; g < 2; ++g) {
        f32x4 a = __builtin_amdgcn_mfma_f32_16x16x32_bf16(kf0, qf[g][0], fz, 0, 0, 0);
        sc4[g][nt] = __builtin_amdgcn_mfma_f32_16x16x32_bf16(kf1, qf[g][1], a, 0, 0, 0);
      }
    }

    // P = exp2(S) unnormalized; accumulate l partial; pack + write P [q][k]
#pragma unroll
    for (int g = 0; g < 2; ++g)
#pragma unroll
      for (int nt = 0; nt < 4; ++nt) {
        float p0 = __builtin_amdgcn_exp2f(sc4[g][nt][0]);
        float p1 = __builtin_amdgcn_exp2f(sc4[g][nt][1]);
        float p2 = __builtin_amdgcn_exp2f(sc4[g][nt][2]);
        float p3 = __builtin_amdgcn_exp2f(sc4[g][nt][3]);
        l_part[g] += (p0 + p1) + (p2 + p3);
        const int pc = (nt * 2 + (quad >> 1)) ^ (lr & 7);
        *reinterpret_cast<uint2*>(&QPs[wave * 32 + g * 16 + lr][pc * 8 + (quad & 1) * 4]) =
            make_uint2(pkbf(p0, p1), pkbf(p2, p3));
      }

    __threadfence_block();   // order P writes before same-wave reads

    bf16x8 pa[2][2];
#pragma unroll
    for (int g = 0; g < 2; ++g) {
      pa[g][0] = *reinterpret_cast<const bf16x8*>(&QPs[wave * 32 + g * 16 + lr][sw0]);
      pa[g][1] = *reinterpret_cast<const bf16x8*>(&QPs[wave * 32 + g * 16 + lr][sw1]);
    }
#pragma unroll
    for (int d = 0; d < 4; ++d) {
      bf16x8 vb0 = *reinterpret_cast<const bf16x8*>(&Vs[buf][d * 16 + lr][sw0]);
      bf16x8 vb1 = *reinterpret_cast<const bf16x8*>(&Vs[buf][d * 16 + lr][sw1]);
#pragma unroll
      for (int g = 0; g < 2; ++g) {
        oacc[g][d] = __builtin_amdgcn_mfma_f32_16x16x32_bf16(pa[g][0], vb0, oacc[g][d], 0, 0, 0);
        oacc[g][d] = __builtin_amdgcn_mfma_f32_16x16x32_bf16(pa[g][1], vb1, oacc[g][d], 0, 0, 0);
      }
    }

    if (++kt == NT) break;
    // single barrier: (a) all waves done reading buf -> safe to overwrite next
    // iter; (b) drains prefetch vmcnt -> buf^1 fully staged for next iter.
    __syncthreads();
  }

  // finalize l: quads covered disjoint keys
#pragma unroll
  for (int g = 0; g < 2; ++g) {
    l_part[g] += __shfl_xor(l_part[g], 16);
    l_part[g] += __shfl_xor(l_part[g], 32);
  }

  const int b = bh >> 4, h = bh & 15;
#pragma unroll
  for (int g = 0; g < 2; ++g) {
    float linv[4];
#pragma unroll
    for (int r = 0; r < 4; ++r) linv[r] = 1.0f / __shfl(l_part[g], quad * 4 + r);
#pragma unroll
    for (int d = 0; d < 4; ++d)
#pragma unroll
      for (int r = 0; r < 4; ++r) {
        const int q = qt * 128 + wave * 32 + g * 16 + quad * 4 + r;
        Ctx[(((size_t)b * SEQ + q) << 10) + h * 64 + d * 16 + lr] =
            f2bf(oacc[g][d][r] * linv[r]);
      }
  }
}

// ---------------- launch ----------------
extern "C" void kernel_launch(void* const* d_in, const int* in_sizes, int n_in,
                              void* d_out, int out_size, void* d_ws, size_t ws_size,
                              hipStream_t stream) {
  const float* X  = (const float*)d_in[0];
  const float* Wq = (const float*)d_in[1];
  const float* bq = (const float*)d_in[2];
  const float* Wk = (const float*)d_in[3];
  const float* bk = (const float*)d_in[4];
  const float* Wv = (const float*)d_in[5];
  const float* bv = (const float*)d_in[6];
  const float* Wo = (const float*)d_in[7];
  const float* bo = (const float*)d_in[8];

  unsigned short* ws = (unsigned short*)d_ws;
  const size_t M1 = (size_t)1024 * 1024;
  unsigned short* Xbf = ws;                 // 4M shorts
  unsigned short* WqT = ws + 4 * M1;        // weights n-major (q,k,v contiguous for fused B)
  unsigned short* WkT = ws + 5 * M1;
  unsigned short* WvT = ws + 6 * M1;
  unsigned short* WoT = ws + 7 * M1;
  unsigned short* Qb  = ws + 8 * M1;
  unsigned short* Kb  = ws + 12 * M1;
  unsigned short* Vt  = ws + 16 * M1;
  unsigned short* Ctx = ws + 20 * M1;       // 48 MB total

  // prep: cast X (4096 blocks) + 4 weight transposes (1024 blocks)
  prep_k<<<5120, 256, 0, stream>>>(X, Xbf, Wq, Wk, Wv, Wo, WqT, WkT, WvT, WoT);

  // fused QKV projection: Bt = [WqT;WkT;WvT], N=3072; 128x128, counted-vmcnt pipeline
  gemm_k<0, 128><<<dim3(MTOK / 128, 3072 / 128), 256, 0, stream>>>(
      Xbf, WqT, bq, bk, bv, Qb, Kb, Vt, nullptr);

  // grid x = bh for XCD-pinned K/V L2 residency; QBLK=128
  attn_k<<<dim3(BATCH * NHEAD, SEQ / 128), 256, 0, stream>>>(Qb, Kb, Vt, Ctx);

  // output projection: 64x128, counted-vmcnt pipeline
  gemm_k<1, 64><<<dim3(MTOK / 64, EMBED / 128), 256, 0, stream>>>(
      Ctx, WoT, bo, nullptr, nullptr, nullptr, nullptr, nullptr, (float*)d_out);
}